// Round 4
// baseline (1331.625 us; speedup 1.0000x reference)
//
#include <hip/hip_runtime.h>
#include <math.h>

#define BB 4
#define SS 1024
#define HH 12
#define DD 32
#define HIDDEN 768
#define AHS 384
#define RQ 8
#define HEAD_ELEMS (SS*DD)      // 32768
#define CTX_ELEMS (BB*SS*AHS)   // 1572864

__device__ __forceinline__ float clampf(float x, float lo, float hi){ return fminf(fmaxf(x, lo), hi); }

// ---------------------------------------------------------------------------
// Kernel 1: fused QKV projection + k-norms. C = X @ W^T + b, 4 weight mats as
// one [4096 x 1536] GEMM. BM128/BN64/BK16, 8x4 micro (best measured density).
// Round-4: DOUBLE-BUFFERED LDS -> one barrier per K-step (was 2); norms for
// k1/k2 computed in-epilogue (BN=64 covers exactly 2 complete heads), so the
// separate norms kernel is gone.
// q,v stored [BH,S,D]; k1,k2 INTERLEAVED [BH, D/4, S, 4].
// ---------------------------------------------------------------------------
__global__ __launch_bounds__(256)
void proj_kernel(const float* __restrict__ X,
                 const float* __restrict__ W0, const float* __restrict__ b0,
                 const float* __restrict__ W1, const float* __restrict__ b1,
                 const float* __restrict__ W2, const float* __restrict__ b2,
                 const float* __restrict__ W3, const float* __restrict__ b3,
                 float* __restrict__ qo, float* __restrict__ k1o,
                 float* __restrict__ k2o, float* __restrict__ vo,
                 float* __restrict__ n1, float* __restrict__ n2)
{
    const int BM = 128, BN = 64, BK = 16;
    __shared__ float Xs[2][BK][BM + 4];
    __shared__ float Wsh[2][BK][BN + 4];
    int t  = threadIdx.x;
    int m0 = blockIdx.x * BM;
    int n0 = blockIdx.y * BN;
    int mat = n0 / AHS;                 // 6 tiles per mat, never straddles
    int c0  = n0 % AHS;
    const float* W    = (mat==0) ? W0 : (mat==1) ? W1 : (mat==2) ? W2 : W3;
    const float* bias = (mat==0) ? b0 : (mat==1) ? b1 : (mat==2) ? b2 : b3;

    int tx = t & 15, ty = t >> 4;       // micro-tile: rows ty*8..+8, cols tx*4..+4
    int lr = t >> 2;                    // 0..63
    int lc = (t & 3) << 2;              // 0,4,8,12

    float acc[8][4];
    #pragma unroll
    for (int i = 0; i < 8; i++)
        #pragma unroll
        for (int j = 0; j < 4; j++) acc[i][j] = 0.f;

    float4 xa = *(const float4*)(X + (m0 + lr) * HIDDEN + lc);
    float4 xb = *(const float4*)(X + (m0 + 64 + lr) * HIDDEN + lc);
    float4 wa = *(const float4*)(W + (c0 + lr) * HIDDEN + lc);

    // prologue: fill buffer 0
    Xs[0][lc+0][lr] = xa.x; Xs[0][lc+1][lr] = xa.y; Xs[0][lc+2][lr] = xa.z; Xs[0][lc+3][lr] = xa.w;
    Xs[0][lc+0][64+lr] = xb.x; Xs[0][lc+1][64+lr] = xb.y; Xs[0][lc+2][64+lr] = xb.z; Xs[0][lc+3][64+lr] = xb.w;
    Wsh[0][lc+0][lr] = wa.x; Wsh[0][lc+1][lr] = wa.y; Wsh[0][lc+2][lr] = wa.z; Wsh[0][lc+3][lr] = wa.w;
    __syncthreads();

    for (int k0 = 0; k0 < HIDDEN; k0 += BK) {
        int cur = (k0 >> 4) & 1;
        bool more = (k0 + BK < HIDDEN);
        if (more) {   // prefetch next tile into regs (latency hidden by compute)
            xa = *(const float4*)(X + (m0 + lr) * HIDDEN + k0 + BK + lc);
            xb = *(const float4*)(X + (m0 + 64 + lr) * HIDDEN + k0 + BK + lc);
            wa = *(const float4*)(W + (c0 + lr) * HIDDEN + k0 + BK + lc);
        }
        #pragma unroll
        for (int kk = 0; kk < BK; kk++) {
            float a[8], w4[4];
            *(float4*)&a[0] = *(const float4*)&Xs[cur][kk][ty << 3];
            *(float4*)&a[4] = *(const float4*)&Xs[cur][kk][(ty << 3) + 4];
            *(float4*)w4    = *(const float4*)&Wsh[cur][kk][tx << 2];
            #pragma unroll
            for (int i = 0; i < 8; i++)
                #pragma unroll
                for (int j = 0; j < 4; j++)
                    acc[i][j] = fmaf(a[i], w4[j], acc[i][j]);
        }
        if (more) {   // write NEXT buffer; one barrier per step
            int nxt = cur ^ 1;
            Xs[nxt][lc+0][lr] = xa.x; Xs[nxt][lc+1][lr] = xa.y; Xs[nxt][lc+2][lr] = xa.z; Xs[nxt][lc+3][lr] = xa.w;
            Xs[nxt][lc+0][64+lr] = xb.x; Xs[nxt][lc+1][64+lr] = xb.y; Xs[nxt][lc+2][64+lr] = xb.z; Xs[nxt][lc+3][64+lr] = xb.w;
            Wsh[nxt][lc+0][lr] = wa.x; Wsh[nxt][lc+1][lr] = wa.y; Wsh[nxt][lc+2][lr] = wa.z; Wsh[nxt][lc+3][lr] = wa.w;
            __syncthreads();
        }
    }

    int cbase = c0 + (tx << 2);          // < 384; one d-quad of one head
    int h  = cbase >> 5;
    int d0 = cbase & 31;
    int d4 = d0 >> 2;
    float4 bq4 = *(const float4*)(bias + cbase);

    float psq[8];
    #pragma unroll
    for (int i = 0; i < 8; i++) {
        int row = m0 + (ty << 3) + i;
        int b_  = row >> 10;
        int s   = row & 1023;
        int bh  = b_ * HH + h;
        float4 val;
        val.x = acc[i][0] + bq4.x;
        val.y = acc[i][1] + bq4.y;
        val.z = acc[i][2] + bq4.z;
        val.w = acc[i][3] + bq4.w;
        psq[i] = val.x*val.x + val.y*val.y + val.z*val.z + val.w*val.w;
        if (mat == 0)
            *(float4*)&qo[((size_t)(bh * SS + s)) * DD + d0] = val;
        else if (mat == 1)
            *(float4*)&k1o[((size_t)(bh * 8 + d4) * SS + s) * 4] = val;
        else if (mat == 2)
            *(float4*)&k2o[((size_t)(bh * 8 + d4) * SS + s) * 4] = val;
        else
            *(float4*)&vo[((size_t)(bh * SS + s)) * DD + d0] = val;
    }

    // ---- fused k-norms (mat 1/2 only; WG-uniform branch) ------------------
    if (mat == 1 || mat == 2) {
        float* nout = (mat == 1) ? n1 : n2;
        float* nrm  = (float*)Xs;        // reuse (needs 2*128*8 = 8 KB)
        __syncthreads();                 // all compute reads of Xs done
        int hs = tx >> 3, q8 = tx & 7;   // head-half, quad-within-head
        #pragma unroll
        for (int i = 0; i < 8; i++)
            nrm[hs * 1024 + ((ty << 3) + i) * 8 + q8] = psq[i];
        __syncthreads();
        // reduce: 256 threads cover 2 heads x 128 rows
        int hs2 = t >> 7, ri = t & 127;
        const float* pn = &nrm[hs2 * 1024 + ri * 8];
        float4 aq = *(const float4*)pn;
        float4 bq = *(const float4*)(pn + 4);
        float s8 = ((aq.x + aq.y) + (aq.z + aq.w)) + ((bq.x + bq.y) + (bq.z + bq.w));
        int row = m0 + ri;
        int b_  = row >> 10;
        int s   = row & 1023;
        int hh  = (c0 >> 5) + hs2;
        nout[(b_ * HH + hh) * SS + s] = s8;
    }
}

// ---------------------------------------------------------------------------
// Kernel 3: FUSED scores + softmax-mixture + ctx = P @ V + probs write.
// Round-4 restructure to KILL SPILLS (VGPR_Count was 64 with ~110 live
// floats -> ~260 MB/dispatch of scratch traffic in earlier rounds):
//  - amdgpu_waves_per_eu(4,4): compiler targets 4 waves/EU -> up to 128 VGPR.
//  - two passes over keys: pass A (k1) writes RAW e1 scores to LDS p_s;
//    pass B (k2) keeps e2 in registers. Peak live ~96 regs.
//  - phase 2 reads e1 back (same-thread addresses, no barrier needed),
//    mixes, writes unnormalized p to LDS and keeps p in regs for the tail
//    probs store. 4b applies 1/sum (re-read from red1 to avoid dynamic-index
//    scratch). Plain stores everywhere (NT direct-HBM ack was a loss).
// ---------------------------------------------------------------------------
__global__ __launch_bounds__(256)
__attribute__((amdgpu_waves_per_eu(4, 4)))
void attn_fused(const float* __restrict__ qg,  const float* __restrict__ k1i,
                const float* __restrict__ k2i,
                const float* __restrict__ n1g, const float* __restrict__ n2g,
                const float* __restrict__ maskg, const float* __restrict__ pig,
                const float* __restrict__ vg,
                float* __restrict__ probs, float* __restrict__ ctx)
{
    const float A1C = 0.08838834764831845f;   // SCALING/2
    const float A2C = 0.13258252147247767f;   // 1.5*SCALING/2
    __shared__ float p_s[RQ * SS];            // 32 KB: e1 raw -> p -> PV partials
    __shared__ float q_s[RQ * DD];
    __shared__ float red1[4][RQ], red2[4][RQ];
    __shared__ float qn_s[RQ];

    int t    = threadIdx.x;
    int lane = t & 63, wid = t >> 6;

    // XCD swizzle: 6144 blocks, 8 XCDs -> 768 consecutive swizzled ids per
    // XCD = 6 consecutive bh (k1+k2+v = 2.3 MB, fits 4 MB L2).
    int bid = blockIdx.x;
    int swz = (bid & 7) * 768 + (bid >> 3);
    int bh  = swz >> 7;
    int s0  = (swz & 127) * RQ;
    int b   = bh / HH, h = bh - b * HH;

    q_s[t] = qg[(bh * SS + s0) * DD + t];
    __syncthreads();
    if (t < RQ) {
        float a = 0.f;
        for (int d = 0; d < DD; d++) { float x = q_s[t * DD + d]; a = fmaf(x, x, a); }
        qn_s[t] = a;
    }
    __syncthreads();

    float pi0 = clampf(pig[h],      1e-6f, 2.0f);
    float pi1 = clampf(pig[HH + h], 1e-6f, 2.0f);

    const float* k1p = k1i + (size_t)bh * (8 * SS * 4);   // [d4][s][4]
    const float* k2p = k2i + (size_t)bh * (8 * SS * 4);
    const float* n1p = n1g + bh * SS;
    const float* n2p = n2g + bh * SS;
    const float* mp  = maskg + b * SS;

    // ---- pass A: k1 scores -> raw e1 into LDS; track pm1 ------------------
    float pm1[RQ];
    #pragma unroll
    for (int r = 0; r < RQ; r++) pm1[r] = -3.4e38f;
    #pragma unroll
    for (int j = 0; j < 4; j++) {
        int k = (j << 8) + t;
        float n1k = n1p[k], mk = mp[k];
        float c1[RQ];
        #pragma unroll
        for (int r = 0; r < RQ; r++) c1[r] = 0.f;
        #pragma unroll
        for (int d4 = 0; d4 < 8; d4++) {
            float4 kq1 = *(const float4*)&k1p[((size_t)d4 * SS + k) * 4];
            const float* kv1 = (const float*)&kq1;
            #pragma unroll
            for (int r = 0; r < RQ; r++) {
                float qv[4];
                *(float4*)qv = *(const float4*)&q_s[r * DD + d4 * 4];
                #pragma unroll
                for (int dd = 0; dd < 4; dd++)
                    c1[r] = fmaf(qv[dd], kv1[dd], c1[r]);
            }
        }
        float pv8[8];
        #pragma unroll
        for (int r = 0; r < RQ; r++) {
            float d1v = fmaxf(fmaf(-2.f, c1[r], qn_s[r] + n1k), 0.f);
            float ev1 = fmaf(-A1C, d1v, mk);
            pv8[r] = ev1;
            pm1[r] = fmaxf(pm1[r], ev1);
        }
        int base = (k << 3) ^ (((k >> 5) & 3) << 3);
        *(float4*)&p_s[base]     = *(float4*)&pv8[0];
        *(float4*)&p_s[base + 4] = *(float4*)&pv8[4];
    }
    #pragma unroll
    for (int off = 32; off >= 1; off >>= 1)
        #pragma unroll
        for (int r = 0; r < RQ; r++) pm1[r] = fmaxf(pm1[r], __shfl_xor(pm1[r], off));
    if (lane == 0) {
        #pragma unroll
        for (int r = 0; r < RQ; r++) red1[wid][r] = pm1[r];
    }
    __syncthreads();
    float m1[RQ];
    #pragma unroll
    for (int r = 0; r < RQ; r++)
        m1[r] = fmaxf(fmaxf(red1[0][r], red1[1][r]), fmaxf(red1[2][r], red1[3][r]));

    // ---- pass B: k2 scores in registers; track pm2 ------------------------
    float e2r[4][RQ];
    float pm2[RQ];
    #pragma unroll
    for (int r = 0; r < RQ; r++) pm2[r] = -3.4e38f;
    #pragma unroll
    for (int j = 0; j < 4; j++) {
        int k = (j << 8) + t;
        float n2k = n2p[k], mk = mp[k];
        float c2[RQ];
        #pragma unroll
        for (int r = 0; r < RQ; r++) c2[r] = 0.f;
        #pragma unroll
        for (int d4 = 0; d4 < 8; d4++) {
            float4 kq2 = *(const float4*)&k2p[((size_t)d4 * SS + k) * 4];
            const float* kv2 = (const float*)&kq2;
            #pragma unroll
            for (int r = 0; r < RQ; r++) {
                float qv[4];
                *(float4*)qv = *(const float4*)&q_s[r * DD + d4 * 4];
                #pragma unroll
                for (int dd = 0; dd < 4; dd++)
                    c2[r] = fmaf(qv[dd], kv2[dd], c2[r]);
            }
        }
        #pragma unroll
        for (int r = 0; r < RQ; r++) {
            float d2v = fmaxf(fmaf(-2.f, c2[r], qn_s[r] + n2k), 0.f);
            float ev2 = fmaf(-A2C, d2v, mk);
            e2r[j][r] = ev2;
            pm2[r] = fmaxf(pm2[r], ev2);
        }
    }
    #pragma unroll
    for (int off = 32; off >= 1; off >>= 1)
        #pragma unroll
        for (int r = 0; r < RQ; r++) pm2[r] = fmaxf(pm2[r], __shfl_xor(pm2[r], off));
    if (lane == 0) {
        #pragma unroll
        for (int r = 0; r < RQ; r++) red2[wid][r] = pm2[r];
    }
    __syncthreads();
    float m2[RQ];
    #pragma unroll
    for (int r = 0; r < RQ; r++)
        m2[r] = fmaxf(fmaxf(red2[0][r], red2[1][r]), fmaxf(red2[2][r], red2[3][r]));

    // ---- phase 2: mix; p -> LDS (and stays in e2r regs for tail store) ----
    float ps[RQ];
    #pragma unroll
    for (int r = 0; r < RQ; r++) ps[r] = 0.f;
    #pragma unroll
    for (int j = 0; j < 4; j++) {
        int k = (j << 8) + t;
        int base = (k << 3) ^ (((k >> 5) & 3) << 3);
        float ev1[8];
        *(float4*)&ev1[0] = *(const float4*)&p_s[base];       // same-thread RAW
        *(float4*)&ev1[4] = *(const float4*)&p_s[base + 4];
        float pv8[8];
        #pragma unroll
        for (int r = 0; r < RQ; r++) {
            float p = pi0 * __expf(ev1[r] - m1[r]) + pi1 * __expf(e2r[j][r] - m2[r]);
            e2r[j][r] = p;           // keep for tail probs store
            pv8[r] = p;
            ps[r] += p;
        }
        *(float4*)&p_s[base]     = *(float4*)&pv8[0];
        *(float4*)&p_s[base + 4] = *(float4*)&pv8[4];
    }
    #pragma unroll
    for (int off = 32; off >= 1; off >>= 1)
        #pragma unroll
        for (int r = 0; r < RQ; r++) ps[r] += __shfl_xor(ps[r], off);
    __syncthreads();                 // red1 reuse + p_s writes visible
    if (lane == 0) {
        #pragma unroll
        for (int r = 0; r < RQ; r++) red1[wid][r] = ps[r];
    }
    __syncthreads();
    float inv[RQ];
    #pragma unroll
    for (int r = 0; r < RQ; r++) {
        float sum = red1[0][r] + red1[1][r] + red1[2][r] + red1[3][r];
        inv[r] = 1.0f / (sum + 1e-6f);
    }

    // ---- phase 4a: partial PV (unnormalized). thread = (ks, c4) -----------
    {
        int ks = t >> 3;                 // k slice: 32 consecutive k
        int c4 = t & 7;                  // d-quad
        int swzc = (ks & 3) << 3;
        const float* vp = vg + bh * HEAD_ELEMS + (c4 << 2);
        float4 acc4[RQ];
        #pragma unroll
        for (int r = 0; r < RQ; r++) acc4[r] = make_float4(0.f, 0.f, 0.f, 0.f);
        #pragma unroll 4
        for (int kk = 0; kk < 32; kk++) {
            int k = (ks << 5) + kk;
            int base = (k << 3) ^ swzc;
            float pr[8];
            *(float4*)&pr[0] = *(const float4*)&p_s[base];
            *(float4*)&pr[4] = *(const float4*)&p_s[base + 4];
            float4 vv = *(const float4*)&vp[k << 5];
            #pragma unroll
            for (int r = 0; r < RQ; r++) {
                acc4[r].x = fmaf(pr[r], vv.x, acc4[r].x);
                acc4[r].y = fmaf(pr[r], vv.y, acc4[r].y);
                acc4[r].z = fmaf(pr[r], vv.z, acc4[r].z);
                acc4[r].w = fmaf(pr[r], vv.w, acc4[r].w);
            }
        }
        __syncthreads();                 // all p reads done; reuse p_s
        #pragma unroll
        for (int r = 0; r < RQ; r++)
            *(float4*)&p_s[((ks << 8) + (r << 5) + (c4 << 2)) ^ ((ks & 3) << 3)] = acc4[r];
    }
    __syncthreads();

    // ---- phase 4b: cross-slice reduce + normalize + ctx store -------------
    {
        int rr = t >> 5, dd = t & 31;
        float o = 0.f;
        #pragma unroll
        for (int s2 = 0; s2 < 32; s2++)
            o += p_s[((s2 << 8) + (rr << 5) + dd) ^ ((s2 & 3) << 3)];
        // re-derive 1/sum from LDS (dynamic rr index into inv[] would spill)
        float sum = red1[0][rr] + red1[1][rr] + red1[2][rr] + red1[3][rr];
        o *= 1.0f / (sum + 1e-6f);
        ctx[((size_t)(b * SS + s0 + rr) * HH + h) * DD + dd] = o;
    }

    // ---- phase 5: probs from regs (no spills now), tail position ----------
    float* prow = probs + (size_t)(bh * SS + s0) * SS;
    #pragma unroll
    for (int j = 0; j < 4; j++) {
        int k = (j << 8) + t;
        #pragma unroll
        for (int r = 0; r < RQ; r++)
            prow[(size_t)r * SS + k] = e2r[j][r] * inv[r];
    }
}

// ---------------------------------------------------------------------------
extern "C" void kernel_launch(void* const* d_in, const int* in_sizes, int n_in,
                              void* d_out, int out_size, void* d_ws, size_t ws_size,
                              hipStream_t stream)
{
    const float* hs   = (const float*)d_in[0];
    const float* mask = (const float*)d_in[1];
    const float* Wq   = (const float*)d_in[2];
    const float* bq   = (const float*)d_in[3];
    const float* Wk1  = (const float*)d_in[4];
    const float* bk1  = (const float*)d_in[5];
    const float* Wk2  = (const float*)d_in[6];
    const float* bk2  = (const float*)d_in[7];
    const float* Wv   = (const float*)d_in[8];
    const float* bv   = (const float*)d_in[9];
    const float* pi   = (const float*)d_in[10];

    float* ws   = (float*)d_ws;
    float* q_ws = ws;
    float* v_ws = ws + (size_t)CTX_ELEMS * 1;
    float* k1T  = ws + (size_t)CTX_ELEMS * 2;
    float* k2T  = ws + (size_t)CTX_ELEMS * 3;
    float* n1   = ws + (size_t)CTX_ELEMS * 4;
    float* n2   = n1 + BB * HH * SS;

    float* ctx   = (float*)d_out;
    float* probs = ctx + CTX_ELEMS;

    proj_kernel<<<dim3(32, 24), 256, 0, stream>>>(hs, Wq, bq, Wk1, bk1, Wk2, bk2,
                                                  Wv, bv, q_ws, k1T, k2T, v_ws,
                                                  n1, n2);
    attn_fused<<<dim3(BB * HH * (SS / RQ)), 256, 0, stream>>>(q_ws, k1T, k2T,
                                                              n1, n2, mask, pi,
                                                              v_ws, probs, ctx);
}

// Round 5
// 519.107 us; speedup vs baseline: 2.5652x; 2.5652x over previous
//
#include <hip/hip_runtime.h>
#include <math.h>

#define BB 4
#define SS 1024
#define HH 12
#define DD 32
#define HIDDEN 768
#define AHS 384
#define RQ 8
#define HEAD_ELEMS (SS*DD)      // 32768
#define CTX_ELEMS (BB*SS*AHS)   // 1572864

__device__ __forceinline__ float clampf(float x, float lo, float hi){ return fminf(fmaxf(x, lo), hi); }

// ---------------------------------------------------------------------------
// Kernel 1: fused QKV projection + k-norms. C = X @ W^T + b, 4 weight mats as
// one [4096 x 1536] GEMM. BM128/BN64/BK16, 8x4 micro. Double-buffered LDS
// (one barrier per K-step); k1/k2 norms computed in-epilogue (BN=64 = exactly
// 2 heads), so no separate norms kernel. Verified correct in round 4.
// q,v stored [BH,S,D]; k1,k2 INTERLEAVED [BH, D/4, S, 4].
// ---------------------------------------------------------------------------
__global__ __launch_bounds__(256)
void proj_kernel(const float* __restrict__ X,
                 const float* __restrict__ W0, const float* __restrict__ b0,
                 const float* __restrict__ W1, const float* __restrict__ b1,
                 const float* __restrict__ W2, const float* __restrict__ b2,
                 const float* __restrict__ W3, const float* __restrict__ b3,
                 float* __restrict__ qo, float* __restrict__ k1o,
                 float* __restrict__ k2o, float* __restrict__ vo,
                 float* __restrict__ n1, float* __restrict__ n2)
{
    const int BM = 128, BN = 64, BK = 16;
    __shared__ float Xs[2][BK][BM + 4];
    __shared__ float Wsh[2][BK][BN + 4];
    int t  = threadIdx.x;
    int m0 = blockIdx.x * BM;
    int n0 = blockIdx.y * BN;
    int mat = n0 / AHS;                 // 6 tiles per mat, never straddles
    int c0  = n0 % AHS;
    const float* W    = (mat==0) ? W0 : (mat==1) ? W1 : (mat==2) ? W2 : W3;
    const float* bias = (mat==0) ? b0 : (mat==1) ? b1 : (mat==2) ? b2 : b3;

    int tx = t & 15, ty = t >> 4;       // micro-tile: rows ty*8..+8, cols tx*4..+4
    int lr = t >> 2;                    // 0..63
    int lc = (t & 3) << 2;              // 0,4,8,12

    float acc[8][4];
    #pragma unroll
    for (int i = 0; i < 8; i++)
        #pragma unroll
        for (int j = 0; j < 4; j++) acc[i][j] = 0.f;

    float4 xa = *(const float4*)(X + (m0 + lr) * HIDDEN + lc);
    float4 xb = *(const float4*)(X + (m0 + 64 + lr) * HIDDEN + lc);
    float4 wa = *(const float4*)(W + (c0 + lr) * HIDDEN + lc);

    // prologue: fill buffer 0
    Xs[0][lc+0][lr] = xa.x; Xs[0][lc+1][lr] = xa.y; Xs[0][lc+2][lr] = xa.z; Xs[0][lc+3][lr] = xa.w;
    Xs[0][lc+0][64+lr] = xb.x; Xs[0][lc+1][64+lr] = xb.y; Xs[0][lc+2][64+lr] = xb.z; Xs[0][lc+3][64+lr] = xb.w;
    Wsh[0][lc+0][lr] = wa.x; Wsh[0][lc+1][lr] = wa.y; Wsh[0][lc+2][lr] = wa.z; Wsh[0][lc+3][lr] = wa.w;
    __syncthreads();

    for (int k0 = 0; k0 < HIDDEN; k0 += BK) {
        int cur = (k0 >> 4) & 1;
        bool more = (k0 + BK < HIDDEN);
        if (more) {   // prefetch next tile into regs (latency hidden by compute)
            xa = *(const float4*)(X + (m0 + lr) * HIDDEN + k0 + BK + lc);
            xb = *(const float4*)(X + (m0 + 64 + lr) * HIDDEN + k0 + BK + lc);
            wa = *(const float4*)(W + (c0 + lr) * HIDDEN + k0 + BK + lc);
        }
        #pragma unroll
        for (int kk = 0; kk < BK; kk++) {
            float a[8], w4[4];
            *(float4*)&a[0] = *(const float4*)&Xs[cur][kk][ty << 3];
            *(float4*)&a[4] = *(const float4*)&Xs[cur][kk][(ty << 3) + 4];
            *(float4*)w4    = *(const float4*)&Wsh[cur][kk][tx << 2];
            #pragma unroll
            for (int i = 0; i < 8; i++)
                #pragma unroll
                for (int j = 0; j < 4; j++)
                    acc[i][j] = fmaf(a[i], w4[j], acc[i][j]);
        }
        if (more) {   // write NEXT buffer; one barrier per step
            int nxt = cur ^ 1;
            Xs[nxt][lc+0][lr] = xa.x; Xs[nxt][lc+1][lr] = xa.y; Xs[nxt][lc+2][lr] = xa.z; Xs[nxt][lc+3][lr] = xa.w;
            Xs[nxt][lc+0][64+lr] = xb.x; Xs[nxt][lc+1][64+lr] = xb.y; Xs[nxt][lc+2][64+lr] = xb.z; Xs[nxt][lc+3][64+lr] = xb.w;
            Wsh[nxt][lc+0][lr] = wa.x; Wsh[nxt][lc+1][lr] = wa.y; Wsh[nxt][lc+2][lr] = wa.z; Wsh[nxt][lc+3][lr] = wa.w;
            __syncthreads();
        }
    }

    int cbase = c0 + (tx << 2);          // < 384; one d-quad of one head
    int h  = cbase >> 5;
    int d0 = cbase & 31;
    int d4 = d0 >> 2;
    float4 bq4 = *(const float4*)(bias + cbase);

    float psq[8];
    #pragma unroll
    for (int i = 0; i < 8; i++) {
        int row = m0 + (ty << 3) + i;
        int b_  = row >> 10;
        int s   = row & 1023;
        int bh  = b_ * HH + h;
        float4 val;
        val.x = acc[i][0] + bq4.x;
        val.y = acc[i][1] + bq4.y;
        val.z = acc[i][2] + bq4.z;
        val.w = acc[i][3] + bq4.w;
        psq[i] = val.x*val.x + val.y*val.y + val.z*val.z + val.w*val.w;
        if (mat == 0)
            *(float4*)&qo[((size_t)(bh * SS + s)) * DD + d0] = val;
        else if (mat == 1)
            *(float4*)&k1o[((size_t)(bh * 8 + d4) * SS + s) * 4] = val;
        else if (mat == 2)
            *(float4*)&k2o[((size_t)(bh * 8 + d4) * SS + s) * 4] = val;
        else
            *(float4*)&vo[((size_t)(bh * SS + s)) * DD + d0] = val;
    }

    // ---- fused k-norms (mat 1/2 only; WG-uniform branch) ------------------
    if (mat == 1 || mat == 2) {
        float* nout = (mat == 1) ? n1 : n2;
        float* nrm  = (float*)Xs;        // reuse (needs 2*128*8 = 8 KB)
        __syncthreads();                 // all compute reads of Xs done
        int hs = tx >> 3, q8 = tx & 7;   // head-half, quad-within-head
        #pragma unroll
        for (int i = 0; i < 8; i++)
            nrm[hs * 1024 + ((ty << 3) + i) * 8 + q8] = psq[i];
        __syncthreads();
        // reduce: 256 threads cover 2 heads x 128 rows
        int hs2 = t >> 7, ri = t & 127;
        const float* pn = &nrm[hs2 * 1024 + ri * 8];
        float4 aq = *(const float4*)pn;
        float4 bq = *(const float4*)(pn + 4);
        float s8 = ((aq.x + aq.y) + (aq.z + aq.w)) + ((bq.x + bq.y) + (bq.z + bq.w));
        int row = m0 + ri;
        int b_  = row >> 10;
        int s   = row & 1023;
        int hh  = (c0 >> 5) + hs2;
        nout[(b_ * HH + hh) * SS + s] = s8;
    }
}

// ---------------------------------------------------------------------------
// Kernel 2: FUSED scores + softmax-mixture + probs write + ctx = P @ V.
// Round-5: RESTORE of the round-2 structure (float4 interleaved k-loads,
// XCD swizzle) with the round-1 store discipline: PLAIN stores, probs
// written in phase 3. Measured history: R1 plain/phase-3 = 210 us @ 89%
// VALU; R2 NT/phase-3 = 232 @ 75%; R3 NT/tail = 242; R4 restructure =
// 1047 (scratch explosion). NT stores and long live ranges are the enemy.
// ---------------------------------------------------------------------------
__global__ __launch_bounds__(256, 4)
void attn_fused(const float* __restrict__ qg,  const float* __restrict__ k1i,
                const float* __restrict__ k2i,
                const float* __restrict__ n1g, const float* __restrict__ n2g,
                const float* __restrict__ maskg, const float* __restrict__ pig,
                const float* __restrict__ vg,
                float* __restrict__ probs, float* __restrict__ ctx)
{
    const float A1C = 0.08838834764831845f;   // SCALING/2
    const float A2C = 0.13258252147247767f;   // 1.5*SCALING/2
    __shared__ float p_s[RQ * SS];            // 32 KB: P tile, then PV partials
    __shared__ float q_s[RQ * DD];
    __shared__ float red1[4][RQ], red2[4][RQ];
    __shared__ float qn_s[RQ];

    int t    = threadIdx.x;
    int lane = t & 63, wid = t >> 6;

    // XCD swizzle: 6144 blocks, 8 XCDs -> each XCD gets 768 consecutive
    // swizzled ids = 6 consecutive bh values (k1+k2+v = 2.3 MB, fits 4 MB L2).
    int bid = blockIdx.x;
    int swz = (bid & 7) * 768 + (bid >> 3);
    int bh  = swz >> 7;
    int s0  = (swz & 127) * RQ;
    int b   = bh / HH, h = bh - b * HH;

    q_s[t] = qg[(bh * SS + s0) * DD + t];
    __syncthreads();
    if (t < RQ) {
        float a = 0.f;
        for (int d = 0; d < DD; d++) { float x = q_s[t * DD + d]; a = fmaf(x, x, a); }
        qn_s[t] = a;
    }
    __syncthreads();

    float pi0 = clampf(pig[h],      1e-6f, 2.0f);
    float pi1 = clampf(pig[HH + h], 1e-6f, 2.0f);

    float e1r[4][RQ], e2r[4][RQ];
    float pm1[RQ], pm2[RQ];
    #pragma unroll
    for (int r = 0; r < RQ; r++) { pm1[r] = -3.4e38f; pm2[r] = -3.4e38f; }

    const float* k1p = k1i + (size_t)bh * (8 * SS * 4);   // [d4][s][4]
    const float* k2p = k2i + (size_t)bh * (8 * SS * 4);
    const float* n1p = n1g + bh * SS;
    const float* n2p = n2g + bh * SS;
    const float* mp  = maskg + b * SS;

    // ---- phase 1: dots + scores -------------------------------------------
    #pragma unroll
    for (int j = 0; j < 4; j++) {
        int k = j * 256 + t;
        float n1k = n1p[k], n2k = n2p[k], mk = mp[k];
        float c1[RQ], c2[RQ];
        #pragma unroll
        for (int r = 0; r < RQ; r++) { c1[r] = 0.f; c2[r] = 0.f; }
        #pragma unroll
        for (int d4 = 0; d4 < 8; d4++) {
            float4 kq1 = *(const float4*)&k1p[((size_t)d4 * SS + k) * 4];
            float4 kq2 = *(const float4*)&k2p[((size_t)d4 * SS + k) * 4];
            const float* kv1 = (const float*)&kq1;
            const float* kv2 = (const float*)&kq2;
            #pragma unroll
            for (int r = 0; r < RQ; r++) {
                float qv[4];
                *(float4*)qv = *(const float4*)&q_s[r * DD + d4 * 4];
                #pragma unroll
                for (int dd = 0; dd < 4; dd++) {
                    c1[r] = fmaf(qv[dd], kv1[dd], c1[r]);
                    c2[r] = fmaf(qv[dd], kv2[dd], c2[r]);
                }
            }
        }
        #pragma unroll
        for (int r = 0; r < RQ; r++) {
            float qn  = qn_s[r];
            float d1v = fmaxf(fmaf(-2.f, c1[r], qn + n1k), 0.f);
            float d2v = fmaxf(fmaf(-2.f, c2[r], qn + n2k), 0.f);
            float ev1 = fmaf(-A1C, d1v, mk);
            float ev2 = fmaf(-A2C, d2v, mk);
            e1r[j][r] = ev1;
            e2r[j][r] = ev2;
            pm1[r] = fmaxf(pm1[r], ev1);
            pm2[r] = fmaxf(pm2[r], ev2);
        }
    }

    // ---- row max (both sets, one barrier pair) ----------------------------
    #pragma unroll
    for (int off = 32; off >= 1; off >>= 1)
        #pragma unroll
        for (int r = 0; r < RQ; r++) {
            pm1[r] = fmaxf(pm1[r], __shfl_xor(pm1[r], off));
            pm2[r] = fmaxf(pm2[r], __shfl_xor(pm2[r], off));
        }
    if (lane == 0) {
        #pragma unroll
        for (int r = 0; r < RQ; r++) { red1[wid][r] = pm1[r]; red2[wid][r] = pm2[r]; }
    }
    __syncthreads();
    float m1[RQ], m2[RQ];
    #pragma unroll
    for (int r = 0; r < RQ; r++) {
        m1[r] = fmaxf(fmaxf(red1[0][r], red1[1][r]), fmaxf(red1[2][r], red1[3][r]));
        m2[r] = fmaxf(fmaxf(red2[0][r], red2[1][r]), fmaxf(red2[2][r], red2[3][r]));
    }

    // ---- phase 2: exp + mixture, row sums ---------------------------------
    float ps[RQ];
    #pragma unroll
    for (int r = 0; r < RQ; r++) ps[r] = 0.f;
    #pragma unroll
    for (int j = 0; j < 4; j++)
        #pragma unroll
        for (int r = 0; r < RQ; r++) {
            float p = pi0 * __expf(e1r[j][r] - m1[r]) + pi1 * __expf(e2r[j][r] - m2[r]);
            e1r[j][r] = p;
            ps[r] += p;
        }

    #pragma unroll
    for (int off = 32; off >= 1; off >>= 1)
        #pragma unroll
        for (int r = 0; r < RQ; r++) ps[r] += __shfl_xor(ps[r], off);
    __syncthreads();
    if (lane == 0) {
        #pragma unroll
        for (int r = 0; r < RQ; r++) red1[wid][r] = ps[r];
    }
    __syncthreads();
    float inv[RQ];
    #pragma unroll
    for (int r = 0; r < RQ; r++) {
        float sum = red1[0][r] + red1[1][r] + red1[2][r] + red1[3][r];
        inv[r] = 1.0f / (sum + 1e-6f);
    }

    // ---- phase 3: normalize + PLAIN probs store + stash P in LDS ----------
    // LDS layout: element (k, r) at float index ((k<<3)+r) ^ (((k>>5)&3)<<3).
    float* prow = probs + (size_t)(bh * SS + s0) * SS;
    #pragma unroll
    for (int j = 0; j < 4; j++) {
        int k = (j << 8) + t;
        float pv8[8];
        #pragma unroll
        for (int r = 0; r < RQ; r++) pv8[r] = e1r[j][r] * inv[r];
        #pragma unroll
        for (int r = 0; r < RQ; r++) prow[(size_t)r * SS + k] = pv8[r];
        int base = (k << 3) ^ (((k >> 5) & 3) << 3);
        *(float4*)&p_s[base]     = *(float4*)&pv8[0];
        *(float4*)&p_s[base + 4] = *(float4*)&pv8[4];
    }
    __syncthreads();

    // ---- phase 4a: partial PV. thread = (ks 0..31, c4 0..7) ---------------
    {
        int ks = t >> 3;                 // k slice: 32 consecutive k
        int c4 = t & 7;                  // d-quad: columns c4*4 .. +4
        int swzc = (ks & 3) << 3;
        const float* vp = vg + bh * HEAD_ELEMS + (c4 << 2);
        float4 acc4[RQ];
        #pragma unroll
        for (int r = 0; r < RQ; r++) acc4[r] = make_float4(0.f, 0.f, 0.f, 0.f);
        #pragma unroll 4
        for (int kk = 0; kk < 32; kk++) {
            int k = (ks << 5) + kk;
            int base = (k << 3) ^ swzc;
            float pr[8];
            *(float4*)&pr[0] = *(const float4*)&p_s[base];
            *(float4*)&pr[4] = *(const float4*)&p_s[base + 4];
            float4 vv = *(const float4*)&vp[k << 5];
            #pragma unroll
            for (int r = 0; r < RQ; r++) {
                acc4[r].x = fmaf(pr[r], vv.x, acc4[r].x);
                acc4[r].y = fmaf(pr[r], vv.y, acc4[r].y);
                acc4[r].z = fmaf(pr[r], vv.z, acc4[r].z);
                acc4[r].w = fmaf(pr[r], vv.w, acc4[r].w);
            }
        }
        __syncthreads();                 // all P reads done; reuse p_s
        // partials: element (ks, r, d) at ((ks<<8)+(r<<5)+d) ^ ((ks&3)<<3)
        #pragma unroll
        for (int r = 0; r < RQ; r++)
            *(float4*)&p_s[((ks << 8) + (r << 5) + (c4 << 2)) ^ ((ks & 3) << 3)] = acc4[r];
    }
    __syncthreads();

    // ---- phase 4b: cross-slice reduce + PLAIN ctx store -------------------
    {
        int rr = t >> 5, dd = t & 31;
        float o = 0.f;
        #pragma unroll
        for (int s2 = 0; s2 < 32; s2++)
            o += p_s[((s2 << 8) + (rr << 5) + dd) ^ ((s2 & 3) << 3)];
        ctx[((size_t)(b * SS + s0 + rr) * HH + h) * DD + dd] = o;
    }
}

// ---------------------------------------------------------------------------
extern "C" void kernel_launch(void* const* d_in, const int* in_sizes, int n_in,
                              void* d_out, int out_size, void* d_ws, size_t ws_size,
                              hipStream_t stream)
{
    const float* hs   = (const float*)d_in[0];
    const float* mask = (const float*)d_in[1];
    const float* Wq   = (const float*)d_in[2];
    const float* bq   = (const float*)d_in[3];
    const float* Wk1  = (const float*)d_in[4];
    const float* bk1  = (const float*)d_in[5];
    const float* Wk2  = (const float*)d_in[6];
    const float* bk2  = (const float*)d_in[7];
    const float* Wv   = (const float*)d_in[8];
    const float* bv   = (const float*)d_in[9];
    const float* pi   = (const float*)d_in[10];

    float* ws   = (float*)d_ws;
    float* q_ws = ws;
    float* v_ws = ws + (size_t)CTX_ELEMS * 1;
    float* k1T  = ws + (size_t)CTX_ELEMS * 2;
    float* k2T  = ws + (size_t)CTX_ELEMS * 3;
    float* n1   = ws + (size_t)CTX_ELEMS * 4;
    float* n2   = n1 + BB * HH * SS;

    float* ctx   = (float*)d_out;
    float* probs = ctx + CTX_ELEMS;

    proj_kernel<<<dim3(32, 24), 256, 0, stream>>>(hs, Wq, bq, Wk1, bk1, Wk2, bk2,
                                                  Wv, bv, q_ws, k1T, k2T, v_ws,
                                                  n1, n2);
    attn_fused<<<dim3(BB * HH * (SS / RQ)), 256, 0, stream>>>(q_ws, k1T, k2T,
                                                              n1, n2, mask, pi,
                                                              v_ws, probs, ctx);
}

// Round 8
// 515.402 us; speedup vs baseline: 2.5837x; 1.0072x over previous
//
#include <hip/hip_runtime.h>
#include <math.h>

#define BB 4
#define SS 1024
#define HH 12
#define DD 32
#define HIDDEN 768
#define AHS 384
#define RQ 8
#define HEAD_ELEMS (SS*DD)      // 32768
#define CTX_ELEMS (BB*SS*AHS)   // 1572864

__device__ __forceinline__ float clampf(float x, float lo, float hi){ return fminf(fmaxf(x, lo), hi); }

// ---------------------------------------------------------------------------
// Kernel 1: fused QKV projection + k-norms. C = X @ W^T + b, 4 weight mats as
// one [4096 x 1536] GEMM.
// Round-8: BM 128->64 at 128 THREADS (BN=64, BK=16 unchanged) -> the 8x4
// micro-tile and its FMA/LDS density are preserved exactly, but the grid
// doubles to 64x24 = 1536 WGs = 6 WGs/CU in 6 independent 2-wave barrier
// domains (was 3 WGs/CU in 4-wave domains): more TLP, less barrier convoy.
// Double-buffered LDS, one barrier per K-step. Norms fused in epilogue.
// q,v stored [BH,S,D]; k1,k2 INTERLEAVED [BH, D/4, S, 4].
// ---------------------------------------------------------------------------
__global__ __launch_bounds__(128)
void proj_kernel(const float* __restrict__ X,
                 const float* __restrict__ W0, const float* __restrict__ b0,
                 const float* __restrict__ W1, const float* __restrict__ b1,
                 const float* __restrict__ W2, const float* __restrict__ b2,
                 const float* __restrict__ W3, const float* __restrict__ b3,
                 float* __restrict__ qo, float* __restrict__ k1o,
                 float* __restrict__ k2o, float* __restrict__ vo,
                 float* __restrict__ n1, float* __restrict__ n2)
{
    const int BM = 64, BN = 64, BK = 16;
    __shared__ float Xs[2][BK][BM + 4];
    __shared__ float Wsh[2][BK][BN + 4];
    int t  = threadIdx.x;                // 0..127
    int m0 = blockIdx.x * BM;
    int n0 = blockIdx.y * BN;
    int mat = n0 / AHS;                  // 6 tiles per mat, never straddles
    int c0  = n0 % AHS;
    const float* W    = (mat==0) ? W0 : (mat==1) ? W1 : (mat==2) ? W2 : W3;
    const float* bias = (mat==0) ? b0 : (mat==1) ? b1 : (mat==2) ? b2 : b3;

    int tx = t & 15, ty = t >> 4;        // micro-tile: rows ty*8..+8 (ty 0..7), cols tx*4..+4
    // staging: idx = i*128+t; row = idx>>2 (0..63), k-quad = (idx&3)<<2
    int sr0 = t >> 2;                    // 0..31
    int sr1 = 32 + (t >> 2);             // 32..63
    int sc  = (t & 3) << 2;              // 0,4,8,12

    float acc[8][4];
    #pragma unroll
    for (int i = 0; i < 8; i++)
        #pragma unroll
        for (int j = 0; j < 4; j++) acc[i][j] = 0.f;

    float4 xa = *(const float4*)(X + (m0 + sr0) * HIDDEN + sc);
    float4 xb = *(const float4*)(X + (m0 + sr1) * HIDDEN + sc);
    float4 wa = *(const float4*)(W + (c0 + sr0) * HIDDEN + sc);
    float4 wb = *(const float4*)(W + (c0 + sr1) * HIDDEN + sc);

    // prologue: fill buffer 0
    Xs[0][sc+0][sr0] = xa.x; Xs[0][sc+1][sr0] = xa.y; Xs[0][sc+2][sr0] = xa.z; Xs[0][sc+3][sr0] = xa.w;
    Xs[0][sc+0][sr1] = xb.x; Xs[0][sc+1][sr1] = xb.y; Xs[0][sc+2][sr1] = xb.z; Xs[0][sc+3][sr1] = xb.w;
    Wsh[0][sc+0][sr0] = wa.x; Wsh[0][sc+1][sr0] = wa.y; Wsh[0][sc+2][sr0] = wa.z; Wsh[0][sc+3][sr0] = wa.w;
    Wsh[0][sc+0][sr1] = wb.x; Wsh[0][sc+1][sr1] = wb.y; Wsh[0][sc+2][sr1] = wb.z; Wsh[0][sc+3][sr1] = wb.w;
    __syncthreads();

    for (int k0 = 0; k0 < HIDDEN; k0 += BK) {
        int cur = (k0 >> 4) & 1;
        bool more = (k0 + BK < HIDDEN);
        if (more) {   // prefetch next tile into regs (latency hidden by compute)
            xa = *(const float4*)(X + (m0 + sr0) * HIDDEN + k0 + BK + sc);
            xb = *(const float4*)(X + (m0 + sr1) * HIDDEN + k0 + BK + sc);
            wa = *(const float4*)(W + (c0 + sr0) * HIDDEN + k0 + BK + sc);
            wb = *(const float4*)(W + (c0 + sr1) * HIDDEN + k0 + BK + sc);
        }
        #pragma unroll
        for (int kk = 0; kk < BK; kk++) {
            float a[8], w4[4];
            *(float4*)&a[0] = *(const float4*)&Xs[cur][kk][ty << 3];
            *(float4*)&a[4] = *(const float4*)&Xs[cur][kk][(ty << 3) + 4];
            *(float4*)w4    = *(const float4*)&Wsh[cur][kk][tx << 2];
            #pragma unroll
            for (int i = 0; i < 8; i++)
                #pragma unroll
                for (int j = 0; j < 4; j++)
                    acc[i][j] = fmaf(a[i], w4[j], acc[i][j]);
        }
        if (more) {   // write NEXT buffer; one barrier per step
            int nxt = cur ^ 1;
            Xs[nxt][sc+0][sr0] = xa.x; Xs[nxt][sc+1][sr0] = xa.y; Xs[nxt][sc+2][sr0] = xa.z; Xs[nxt][sc+3][sr0] = xa.w;
            Xs[nxt][sc+0][sr1] = xb.x; Xs[nxt][sc+1][sr1] = xb.y; Xs[nxt][sc+2][sr1] = xb.z; Xs[nxt][sc+3][sr1] = xb.w;
            Wsh[nxt][sc+0][sr0] = wa.x; Wsh[nxt][sc+1][sr0] = wa.y; Wsh[nxt][sc+2][sr0] = wa.z; Wsh[nxt][sc+3][sr0] = wa.w;
            Wsh[nxt][sc+0][sr1] = wb.x; Wsh[nxt][sc+1][sr1] = wb.y; Wsh[nxt][sc+2][sr1] = wb.z; Wsh[nxt][sc+3][sr1] = wb.w;
            __syncthreads();
        }
    }

    int cbase = c0 + (tx << 2);          // < 384; one d-quad of one head
    int h  = cbase >> 5;
    int d0 = cbase & 31;
    int d4 = d0 >> 2;
    float4 bq4 = *(const float4*)(bias + cbase);

    float psq[8];
    #pragma unroll
    for (int i = 0; i < 8; i++) {
        int row = m0 + (ty << 3) + i;
        int b_  = row >> 10;
        int s   = row & 1023;
        int bh  = b_ * HH + h;
        float4 val;
        val.x = acc[i][0] + bq4.x;
        val.y = acc[i][1] + bq4.y;
        val.z = acc[i][2] + bq4.z;
        val.w = acc[i][3] + bq4.w;
        psq[i] = val.x*val.x + val.y*val.y + val.z*val.z + val.w*val.w;
        if (mat == 0)
            *(float4*)&qo[((size_t)(bh * SS + s)) * DD + d0] = val;
        else if (mat == 1)
            *(float4*)&k1o[((size_t)(bh * 8 + d4) * SS + s) * 4] = val;
        else if (mat == 2)
            *(float4*)&k2o[((size_t)(bh * 8 + d4) * SS + s) * 4] = val;
        else
            *(float4*)&vo[((size_t)(bh * SS + s)) * DD + d0] = val;
    }

    // ---- fused k-norms (mat 1/2 only; WG-uniform branch) ------------------
    // Stage per-(row, head) quad partials through Xs (needs 2*64*8 = 1024
    // floats; Xs has 2176), then 128 threads reduce 2 heads x 64 rows.
    if (mat == 1 || mat == 2) {
        float* nout = (mat == 1) ? n1 : n2;
        float* nrm  = (float*)Xs;
        __syncthreads();                 // all compute reads of Xs done
        int hs = tx >> 3, q8 = tx & 7;   // head-half, quad-within-head
        #pragma unroll
        for (int i = 0; i < 8; i++)
            nrm[hs * 512 + ((ty << 3) + i) * 8 + q8] = psq[i];
        __syncthreads();
        int hs2 = t >> 6, ri = t & 63;   // head-half, row
        const float* pn = &nrm[hs2 * 512 + ri * 8];
        float4 aq = *(const float4*)pn;
        float4 bq = *(const float4*)(pn + 4);
        float s8 = ((aq.x + aq.y) + (aq.z + aq.w)) + ((bq.x + bq.y) + (bq.z + bq.w));
        int row = m0 + ri;
        int b_  = row >> 10;
        int s   = row & 1023;
        int hh  = (c0 >> 5) + hs2;
        nout[(b_ * HH + hh) * SS + s] = s8;
    }
}

// ---------------------------------------------------------------------------
// Kernel 2: FUSED scores + softmax-mixture + probs write + ctx = P @ V.
// CHAMPION config (round-5, 235 us): float4 interleaved k-loads, XCD swizzle,
// plain stores with probs in phase 3. Byte-identical to R5.
// ---------------------------------------------------------------------------
__global__ __launch_bounds__(256, 4)
void attn_fused(const float* __restrict__ qg,  const float* __restrict__ k1i,
                const float* __restrict__ k2i,
                const float* __restrict__ n1g, const float* __restrict__ n2g,
                const float* __restrict__ maskg, const float* __restrict__ pig,
                const float* __restrict__ vg,
                float* __restrict__ probs, float* __restrict__ ctx)
{
    const float A1C = 0.08838834764831845f;   // SCALING/2
    const float A2C = 0.13258252147247767f;   // 1.5*SCALING/2
    __shared__ float p_s[RQ * SS];            // 32 KB: P tile, then PV partials
    __shared__ float q_s[RQ * DD];
    __shared__ float red1[4][RQ], red2[4][RQ];
    __shared__ float qn_s[RQ];

    int t    = threadIdx.x;
    int lane = t & 63, wid = t >> 6;

    int bid = blockIdx.x;
    int swz = (bid & 7) * 768 + (bid >> 3);
    int bh  = swz >> 7;
    int s0  = (swz & 127) * RQ;
    int b   = bh / HH, h = bh - b * HH;

    q_s[t] = qg[(bh * SS + s0) * DD + t];
    __syncthreads();
    if (t < RQ) {
        float a = 0.f;
        for (int d = 0; d < DD; d++) { float x = q_s[t * DD + d]; a = fmaf(x, x, a); }
        qn_s[t] = a;
    }
    __syncthreads();

    float pi0 = clampf(pig[h],      1e-6f, 2.0f);
    float pi1 = clampf(pig[HH + h], 1e-6f, 2.0f);

    float e1r[4][RQ], e2r[4][RQ];
    float pm1[RQ], pm2[RQ];
    #pragma unroll
    for (int r = 0; r < RQ; r++) { pm1[r] = -3.4e38f; pm2[r] = -3.4e38f; }

    const float* k1p = k1i + (size_t)bh * (8 * SS * 4);   // [d4][s][4]
    const float* k2p = k2i + (size_t)bh * (8 * SS * 4);
    const float* n1p = n1g + bh * SS;
    const float* n2p = n2g + bh * SS;
    const float* mp  = maskg + b * SS;

    // ---- phase 1: dots + scores -------------------------------------------
    #pragma unroll
    for (int j = 0; j < 4; j++) {
        int k = j * 256 + t;
        float n1k = n1p[k], n2k = n2p[k], mk = mp[k];
        float c1[RQ], c2[RQ];
        #pragma unroll
        for (int r = 0; r < RQ; r++) { c1[r] = 0.f; c2[r] = 0.f; }
        #pragma unroll
        for (int d4 = 0; d4 < 8; d4++) {
            float4 kq1 = *(const float4*)&k1p[((size_t)d4 * SS + k) * 4];
            float4 kq2 = *(const float4*)&k2p[((size_t)d4 * SS + k) * 4];
            const float* kv1 = (const float*)&kq1;
            const float* kv2 = (const float*)&kq2;
            #pragma unroll
            for (int r = 0; r < RQ; r++) {
                float qv[4];
                *(float4*)qv = *(const float4*)&q_s[r * DD + d4 * 4];
                #pragma unroll
                for (int dd = 0; dd < 4; dd++) {
                    c1[r] = fmaf(qv[dd], kv1[dd], c1[r]);
                    c2[r] = fmaf(qv[dd], kv2[dd], c2[r]);
                }
            }
        }
        #pragma unroll
        for (int r = 0; r < RQ; r++) {
            float qn  = qn_s[r];
            float d1v = fmaxf(fmaf(-2.f, c1[r], qn + n1k), 0.f);
            float d2v = fmaxf(fmaf(-2.f, c2[r], qn + n2k), 0.f);
            float ev1 = fmaf(-A1C, d1v, mk);
            float ev2 = fmaf(-A2C, d2v, mk);
            e1r[j][r] = ev1;
            e2r[j][r] = ev2;
            pm1[r] = fmaxf(pm1[r], ev1);
            pm2[r] = fmaxf(pm2[r], ev2);
        }
    }

    // ---- row max (both sets, one barrier pair) ----------------------------
    #pragma unroll
    for (int off = 32; off >= 1; off >>= 1)
        #pragma unroll
        for (int r = 0; r < RQ; r++) {
            pm1[r] = fmaxf(pm1[r], __shfl_xor(pm1[r], off));
            pm2[r] = fmaxf(pm2[r], __shfl_xor(pm2[r], off));
        }
    if (lane == 0) {
        #pragma unroll
        for (int r = 0; r < RQ; r++) { red1[wid][r] = pm1[r]; red2[wid][r] = pm2[r]; }
    }
    __syncthreads();
    float m1[RQ], m2[RQ];
    #pragma unroll
    for (int r = 0; r < RQ; r++) {
        m1[r] = fmaxf(fmaxf(red1[0][r], red1[1][r]), fmaxf(red1[2][r], red1[3][r]));
        m2[r] = fmaxf(fmaxf(red2[0][r], red2[1][r]), fmaxf(red2[2][r], red2[3][r]));
    }

    // ---- phase 2: exp + mixture, row sums ---------------------------------
    float ps[RQ];
    #pragma unroll
    for (int r = 0; r < RQ; r++) ps[r] = 0.f;
    #pragma unroll
    for (int j = 0; j < 4; j++)
        #pragma unroll
        for (int r = 0; r < RQ; r++) {
            float p = pi0 * __expf(e1r[j][r] - m1[r]) + pi1 * __expf(e2r[j][r] - m2[r]);
            e1r[j][r] = p;
            ps[r] += p;
        }

    #pragma unroll
    for (int off = 32; off >= 1; off >>= 1)
        #pragma unroll
        for (int r = 0; r < RQ; r++) ps[r] += __shfl_xor(ps[r], off);
    __syncthreads();
    if (lane == 0) {
        #pragma unroll
        for (int r = 0; r < RQ; r++) red1[wid][r] = ps[r];
    }
    __syncthreads();
    float inv[RQ];
    #pragma unroll
    for (int r = 0; r < RQ; r++) {
        float sum = red1[0][r] + red1[1][r] + red1[2][r] + red1[3][r];
        inv[r] = 1.0f / (sum + 1e-6f);
    }

    // ---- phase 3: normalize + PLAIN probs store + stash P in LDS ----------
    float* prow = probs + (size_t)(bh * SS + s0) * SS;
    #pragma unroll
    for (int j = 0; j < 4; j++) {
        int k = (j << 8) + t;
        float pv8[8];
        #pragma unroll
        for (int r = 0; r < RQ; r++) pv8[r] = e1r[j][r] * inv[r];
        #pragma unroll
        for (int r = 0; r < RQ; r++) prow[(size_t)r * SS + k] = pv8[r];
        int base = (k << 3) ^ (((k >> 5) & 3) << 3);
        *(float4*)&p_s[base]     = *(float4*)&pv8[0];
        *(float4*)&p_s[base + 4] = *(float4*)&pv8[4];
    }
    __syncthreads();

    // ---- phase 4a: partial PV. thread = (ks 0..31, c4 0..7) ---------------
    {
        int ks = t >> 3;
        int c4 = t & 7;
        int swzc = (ks & 3) << 3;
        const float* vp = vg + bh * HEAD_ELEMS + (c4 << 2);
        float4 acc4[RQ];
        #pragma unroll
        for (int r = 0; r < RQ; r++) acc4[r] = make_float4(0.f, 0.f, 0.f, 0.f);
        #pragma unroll 4
        for (int kk = 0; kk < 32; kk++) {
            int k = (ks << 5) + kk;
            int base = (k << 3) ^ swzc;
            float pr[8];
            *(float4*)&pr[0] = *(const float4*)&p_s[base];
            *(float4*)&pr[4] = *(const float4*)&p_s[base + 4];
            float4 vv = *(const float4*)&vp[k << 5];
            #pragma unroll
            for (int r = 0; r < RQ; r++) {
                acc4[r].x = fmaf(pr[r], vv.x, acc4[r].x);
                acc4[r].y = fmaf(pr[r], vv.y, acc4[r].y);
                acc4[r].z = fmaf(pr[r], vv.z, acc4[r].z);
                acc4[r].w = fmaf(pr[r], vv.w, acc4[r].w);
            }
        }
        __syncthreads();
        #pragma unroll
        for (int r = 0; r < RQ; r++)
            *(float4*)&p_s[((ks << 8) + (r << 5) + (c4 << 2)) ^ ((ks & 3) << 3)] = acc4[r];
    }
    __syncthreads();

    // ---- phase 4b: cross-slice reduce + PLAIN ctx store -------------------
    {
        int rr = t >> 5, dd = t & 31;
        float o = 0.f;
        #pragma unroll
        for (int s2 = 0; s2 < 32; s2++)
            o += p_s[((s2 << 8) + (rr << 5) + dd) ^ ((s2 & 3) << 3)];
        ctx[((size_t)(b * SS + s0 + rr) * HH + h) * DD + dd] = o;
    }
}

// ---------------------------------------------------------------------------
extern "C" void kernel_launch(void* const* d_in, const int* in_sizes, int n_in,
                              void* d_out, int out_size, void* d_ws, size_t ws_size,
                              hipStream_t stream)
{
    const float* hs   = (const float*)d_in[0];
    const float* mask = (const float*)d_in[1];
    const float* Wq   = (const float*)d_in[2];
    const float* bq   = (const float*)d_in[3];
    const float* Wk1  = (const float*)d_in[4];
    const float* bk1  = (const float*)d_in[5];
    const float* Wk2  = (const float*)d_in[6];
    const float* bk2  = (const float*)d_in[7];
    const float* Wv   = (const float*)d_in[8];
    const float* bv   = (const float*)d_in[9];
    const float* pi   = (const float*)d_in[10];

    float* ws   = (float*)d_ws;
    float* q_ws = ws;
    float* v_ws = ws + (size_t)CTX_ELEMS * 1;
    float* k1T  = ws + (size_t)CTX_ELEMS * 2;
    float* k2T  = ws + (size_t)CTX_ELEMS * 3;
    float* n1   = ws + (size_t)CTX_ELEMS * 4;
    float* n2   = n1 + BB * HH * SS;

    float* ctx   = (float*)d_out;
    float* probs = ctx + CTX_ELEMS;

    proj_kernel<<<dim3(64, 24), 128, 0, stream>>>(hs, Wq, bq, Wk1, bk1, Wk2, bk2,
                                                  Wv, bv, q_ws, k1T, k2T, v_ws,
                                                  n1, n2);
    attn_fused<<<dim3(BB * HH * (SS / RQ)), 256, 0, stream>>>(q_ws, k1T, k2T,
                                                              n1, n2, mask, pi,
                                                              v_ws, probs, ctx);
}